// Round 2
// baseline (343.489 us; speedup 1.0000x reference)
//
#include <hip/hip_runtime.h>
#include <hip/hip_bf16.h>

typedef __attribute__((ext_vector_type(8))) __bf16 bf16x8;
typedef __attribute__((ext_vector_type(4))) float f32x4;

constexpr int CI_ = 16, CO_ = 64, H_ = 256, W_ = 256;
constexpr int WTROW = 168;      // padded K (144 -> 168) in bf16 elems; 336B rows
constexpr int RSZ = 258 * 32;   // bytes per kh row-region in xs (258 wp * 32B)

// XOR swizzle: spread 16B chunks of rows 4-apart across banks. Bijective
// (flips addr bits 4..6 with bits 7..9); identity on the partial last line.
__device__ __forceinline__ unsigned swz(unsigned o) {
  return o ^ (((o >> 7) & 7u) << 4);
}

// NCHW fp32 -> NHWC bf16: xt[n][h][w][ci]; 4 pixels per thread, float4 loads
__global__ void transform_x_kernel(const float* __restrict__ x,
                                   unsigned short* __restrict__ xt) {
  int t = blockIdx.x * 256 + threadIdx.x;  // 262144 threads
  int p0 = t << 2;                         // base pixel (n,h,w), w%4==0
  int w = p0 & 255;
  int h = (p0 >> 8) & 255;
  int n = p0 >> 16;
  const float* src = x + ((size_t)n * CI_) * (H_ * W_) + h * W_ + w;
  unsigned short tmp[64];  // [4 pixels][16 ci]
#pragma unroll
  for (int ci = 0; ci < 16; ++ci) {
    float4 v = *(const float4*)(src + (size_t)ci * (H_ * W_));
    tmp[0 * 16 + ci] = __builtin_bit_cast(unsigned short, (__bf16)v.x);
    tmp[1 * 16 + ci] = __builtin_bit_cast(unsigned short, (__bf16)v.y);
    tmp[2 * 16 + ci] = __builtin_bit_cast(unsigned short, (__bf16)v.z);
    tmp[3 * 16 + ci] = __builtin_bit_cast(unsigned short, (__bf16)v.w);
  }
  uint4* dst = (uint4*)(xt + (size_t)p0 * 16);
#pragma unroll
  for (int q = 0; q < 8; ++q) dst[q] = ((const uint4*)tmp)[q];
}

// OIHW fp32 -> wt[co][k], k = tap*16 + ci, padded/zeroed to 168
__global__ void transform_w_kernel(const float* __restrict__ Wg,
                                   unsigned short* __restrict__ wt) {
  int idx = blockIdx.x * 256 + threadIdx.x;  // 64*168 = 10752 exact
  int co = idx / WTROW;
  int kk = idx - co * WTROW;
  float v = 0.f;
  if (kk < 144) {
    int t = kk >> 4;  // tap = kh*3+kw
    int ci = kk & 15;
    v = Wg[(co * 16 + ci) * 9 + t];
  }
  wt[idx] = __builtin_bit_cast(unsigned short, (__bf16)v);
}

// one block per (n,h): computes out[n][0..63][h][0..255]
__global__ __launch_bounds__(256) void conv_mfma_kernel(
    const unsigned short* __restrict__ xt, const unsigned short* __restrict__ wt,
    float* __restrict__ out) {
  __shared__ unsigned char xs[3 * RSZ];        // 24768 B, XOR-swizzled rows
  __shared__ unsigned short wlds[CO_][WTROW];  // 21504 B

  int tid = threadIdx.x;
  int bid = blockIdx.x;
  int h = bid & 255;
  int n = bid >> 8;

  // stage weights: 21504 B = 1344 uint4
  {
    const uint4* src = (const uint4*)wt;
    uint4* dst = (uint4*)&wlds[0][0];
    for (int c = tid; c < 1344; c += 256) dst[c] = src[c];
  }
  // stage 3 input rows (512 x 16B chunks each), swizzled, zero out-of-range
  {
    const uint4* srcbase = (const uint4*)xt;  // one uint4 = 8 ci values
    for (int c = tid; c < 1536; c += 256) {
      int r = c >> 9;     // 0..2
      int j = c & 511;    // chunk within row; wp = 1 + (j>>1)
      int hh = h - 1 + r;
      uint4 v = make_uint4(0u, 0u, 0u, 0u);
      if (hh >= 0 && hh < 256)
        v = srcbase[(size_t)(n * 256 + hh) * 512 + j];
      *(uint4*)(xs + r * RSZ + swz(32u + 16u * (unsigned)j)) = v;
    }
    if (tid < 12) {  // zero pad columns wp=0 and wp=257 (2 chunks each, 3 rows)
      int r = tid >> 2;
      int q = tid & 3;
      unsigned off = ((q >> 1) ? 257u * 32u : 0u) + (q & 1) * 16u;
      *(uint4*)(xs + r * RSZ + swz(off)) = make_uint4(0u, 0u, 0u, 0u);
    }
  }
  __syncthreads();

  int lane = tid & 63;
  int wave = tid >> 6;
  int col = lane & 15;  // MFMA column index
  int g = lane >> 4;    // 0..3 k-group

  f32x4 acc[4][4];
#pragma unroll
  for (int i = 0; i < 4; ++i)
#pragma unroll
    for (int j = 0; j < 4; ++j) acc[i][j] = (f32x4){0.f, 0.f, 0.f, 0.f};

  int pxb = wave * 64 + 4 * col;  // lane's base pixel; tile pb holds pixel pxb+pb

#pragma unroll
  for (int s = 0; s < 5; ++s) {
    bf16x8 a[4];
#pragma unroll
    for (int cb = 0; cb < 4; ++cb)
      a[cb] = *(const bf16x8*)&wlds[cb * 16 + col][s * 32 + 8 * g];

    int tap = 2 * s + (g >> 1);
    if (tap > 8) tap = 8;  // k>=144: A is zero, B value irrelevant
    int kh = tap / 3;      // xs row-region index (dh+1)
    int kw = tap - kh * 3; // wp offset
    int ci0 = (g & 1) * 8;

    bf16x8 b[4];
#pragma unroll
    for (int pb = 0; pb < 4; ++pb) {
      unsigned wp = (unsigned)(pxb + pb + kw);  // padded row index
      b[pb] = *(const bf16x8*)(xs + kh * RSZ + swz(wp * 32u + ci0 * 2u));
    }

#pragma unroll
    for (int cb = 0; cb < 4; ++cb)
#pragma unroll
      for (int pb = 0; pb < 4; ++pb)
        acc[cb][pb] = __builtin_amdgcn_mfma_f32_16x16x32_bf16(
            a[cb], b[pb], acc[cb][pb], 0, 0, 0);
  }

  // D layout: col = lane&15, row = g*4 + reg. Lane's pb entries are pixels
  // pxb+0..3 -> contiguous float4 store per (cb, r).
  size_t obase = ((size_t)n * CO_ * H_ + h) * W_ + pxb;
#pragma unroll
  for (int cb = 0; cb < 4; ++cb) {
#pragma unroll
    for (int r = 0; r < 4; ++r) {
      int co = cb * 16 + g * 4 + r;
      f32x4 v = {acc[cb][0][r], acc[cb][1][r], acc[cb][2][r], acc[cb][3][r]};
      *(f32x4*)(out + obase + (size_t)co * (H_ * W_)) = v;
    }
  }
}

extern "C" void kernel_launch(void* const* d_in, const int* in_sizes, int n_in,
                              void* d_out, int out_size, void* d_ws, size_t ws_size,
                              hipStream_t stream) {
  const float* x = (const float*)d_in[0];  // [16,16,256,256]
  const float* W = (const float*)d_in[1];  // [64,16,3,3]
  float* out = (float*)d_out;              // [16,64,256,256]

  unsigned short* xt = (unsigned short*)d_ws;            // 32 MB bf16 NHWC
  unsigned short* wt = xt + (size_t)16 * 256 * 256 * 16; // 10752 bf16

  transform_x_kernel<<<1024, 256, 0, stream>>>(x, xt);
  transform_w_kernel<<<42, 256, 0, stream>>>(W, wt);
  conv_mfma_kernel<<<4096, 256, 0, stream>>>(xt, wt, out);
}